// Round 1
// baseline (94.108 us; speedup 1.0000x reference)
//
#include <hip/hip_runtime.h>
#include <hip/hip_bf16.h>

#define N_ATOMS_MAX 20000
#define NN 64
#define N_TYPES 4
#define N_DESC 8
#define K_MAX 8
#define R_C 8.0f

// One wave (64 lanes) per atom; lane j handles neighbor j.
// Block = 256 threads = 4 atoms/block.
__global__ __launch_bounds__(256) void radial_desc_kernel(
    const int* __restrict__ types,            // [N_ATOMS]
    const float* __restrict__ positions,      // [N_ATOMS][3]
    const int* __restrict__ radial_neighbors, // [N_ATOMS][NN]
    const float* __restrict__ radial_offsets, // [N_ATOMS][NN][3]
    const float* __restrict__ c_table,        // [N_TYPES][N_TYPES][N_DESC][K_MAX]
    float* __restrict__ out,                  // [N_ATOMS][N_DESC]
    int n_atoms)
{
    // LDS copy of c_table, transposed to [d*K + k][ta*4 + tn] so that for a
    // fixed (d,k) the 4 possible (ta,tn) values are CONSECUTIVE addresses:
    // lanes with different tn hit different banks (no same-bank conflict),
    // lanes with equal tn broadcast.
    __shared__ float ld_c[N_DESC * K_MAX * N_TYPES * N_TYPES]; // 1024 floats = 4KB

    const int tid = threadIdx.x;
    #pragma unroll
    for (int i = tid; i < N_DESC * K_MAX * N_TYPES * N_TYPES; i += 256) {
        const int dk = i >> 4;        // d*8+k
        const int tt = i & 15;        // ta*4+tn
        ld_c[i] = c_table[tt * (N_DESC * K_MAX) + dk];
    }
    __syncthreads();

    const int wave = tid >> 6;
    const int lane = tid & 63;
    const int a = blockIdx.x * 4 + wave;
    if (a >= n_atoms) return;

    // ---- loads ----
    const int nb = radial_neighbors[a * NN + lane];
    const bool valid = (nb != -1);
    const int safe = valid ? nb : 0;

    const float3 off = *reinterpret_cast<const float3*>(radial_offsets + (size_t)(a * NN + lane) * 3);
    const float3 pn  = *reinterpret_cast<const float3*>(positions + (size_t)safe * 3);
    const float3 pa  = *reinterpret_cast<const float3*>(positions + (size_t)a * 3);

    const int ta = types[a];
    const int tn = types[safe];

    // ---- distance ----
    const float dx = pn.x + off.x - pa.x;
    const float dy = pn.y + off.y - pa.y;
    const float dz = pn.z + off.z - pa.z;
    const float r  = sqrtf(dx * dx + dy * dy + dz * dz);

    // ---- Chebyshev basis ----
    const float rr = r * (1.0f / R_C);
    // fc = 0.5*cos(pi*r/rc)+0.5 for r<rc else 0; fold the 0.5 of (0.5*fc):
    const float cosp = __cosf(3.14159265358979323846f * rr);
    const float half_fc = (valid && (r < R_C)) ? (0.25f * cosp + 0.25f) : 0.0f;

    const float x = 2.0f * (rr - 1.0f) * (rr - 1.0f) - 1.0f;

    float fn[K_MAX];
    fn[0] = 1.0f;
    fn[1] = x;
    #pragma unroll
    for (int k = 2; k < K_MAX; ++k)
        fn[k] = 2.0f * x * fn[k - 1] - fn[k - 2];

    float f[K_MAX];
    #pragma unroll
    for (int k = 0; k < K_MAX; ++k)
        f[k] = (fn[k] + 1.0f) * half_fc;

    // ---- per-edge matvec: acc[d] = sum_k c[ta][tn][d][k] * f[k] ----
    const int cb = ta * N_TYPES + tn;
    float acc[N_DESC];
    #pragma unroll
    for (int d = 0; d < N_DESC; ++d) {
        float s = 0.0f;
        #pragma unroll
        for (int k = 0; k < K_MAX; ++k)
            s += ld_c[(d * K_MAX + k) * 16 + cb] * f[k];
        acc[d] = s;
    }

    // ---- reduce across the 64 lanes (neighbors) ----
    #pragma unroll
    for (int d = 0; d < N_DESC; ++d) {
        float v = acc[d];
        #pragma unroll
        for (int s = 1; s < 64; s <<= 1)
            v += __shfl_xor(v, s, 64);
        acc[d] = v;
    }

    if (lane == 0) {
        float4* o4 = reinterpret_cast<float4*>(out + (size_t)a * N_DESC);
        o4[0] = make_float4(acc[0], acc[1], acc[2], acc[3]);
        o4[1] = make_float4(acc[4], acc[5], acc[6], acc[7]);
    }
}

extern "C" void kernel_launch(void* const* d_in, const int* in_sizes, int n_in,
                              void* d_out, int out_size, void* d_ws, size_t ws_size,
                              hipStream_t stream) {
    const int*   types            = (const int*)d_in[0];
    const float* positions        = (const float*)d_in[1];
    const int*   radial_neighbors = (const int*)d_in[2];
    const float* radial_offsets   = (const float*)d_in[3];
    const float* c_table          = (const float*)d_in[4];
    float* out = (float*)d_out;

    const int n_atoms = in_sizes[0];
    const int blocks = (n_atoms + 3) / 4;
    radial_desc_kernel<<<blocks, 256, 0, stream>>>(
        types, positions, radial_neighbors, radial_offsets, c_table, out, n_atoms);
}

// Round 2
// 93.132 us; speedup vs baseline: 1.0105x; 1.0105x over previous
//
#include <hip/hip_runtime.h>
#include <hip/hip_bf16.h>

#define NN 64
#define N_TYPES 4
#define N_DESC 8
#define K_MAX 8
#define R_C 8.0f

// Pre-pack kernel: pos_type[a] = {x, y, z, bitcast(type)} so the main kernel
// does ONE aligned 16B gather per edge instead of two (12B pos + 4B type).
__global__ __launch_bounds__(256) void pack_pos_type(
    const int* __restrict__ types,
    const float* __restrict__ positions,
    float4* __restrict__ packed,
    int n_atoms)
{
    const int a = blockIdx.x * 256 + threadIdx.x;
    if (a >= n_atoms) return;
    const float* p = positions + (size_t)a * 3;
    packed[a] = make_float4(p[0], p[1], p[2], __int_as_float(types[a]));
}

// One wave (64 lanes) per atom; lane j handles neighbor j.
__global__ __launch_bounds__(256) void radial_desc_kernel(
    const float4* __restrict__ packed,        // [N_ATOMS] {x,y,z,type}
    const int* __restrict__ radial_neighbors, // [N_ATOMS][NN]
    const float* __restrict__ radial_offsets, // [N_ATOMS][NN][3]
    const float* __restrict__ c_table,        // [N_TYPES][N_TYPES][N_DESC][K_MAX]
    float* __restrict__ out,                  // [N_ATOMS][N_DESC]
    int n_atoms)
{
    // LDS copy of c_table, layout [d*K+k][ta*4+tn]: for fixed (d,k) the 16
    // possible (ta,tn) slots are consecutive -> 16 distinct banks, same-slot
    // lanes broadcast. Conflict-free.
    __shared__ float ld_c[N_DESC * K_MAX * N_TYPES * N_TYPES]; // 4 KB

    const int tid = threadIdx.x;
    for (int i = tid; i < N_DESC * K_MAX * N_TYPES * N_TYPES; i += 256) {
        const int dk = i >> 4;
        const int tt = i & 15;
        ld_c[i] = c_table[tt * (N_DESC * K_MAX) + dk];
    }
    __syncthreads();

    const int wave = tid >> 6;
    const int lane = tid & 63;
    const int a = blockIdx.x * 4 + wave;
    if (a >= n_atoms) return;

    // ---- loads (issue the independent ones first) ----
    const int nb = radial_neighbors[a * NN + lane];
    const float3 off = *reinterpret_cast<const float3*>(radial_offsets + (size_t)(a * NN + lane) * 3);
    const float4 pta = packed[a];                  // broadcast (one line)
    const bool valid = (nb != -1);
    const int safe = valid ? nb : 0;
    const float4 ptn = packed[safe];               // the gather

    const int ta = __float_as_int(pta.w);
    const int tn = __float_as_int(ptn.w);

    // ---- distance ----
    const float dx = ptn.x + off.x - pta.x;
    const float dy = ptn.y + off.y - pta.y;
    const float dz = ptn.z + off.z - pta.z;
    const float r  = sqrtf(dx * dx + dy * dy + dz * dz);

    // ---- Chebyshev basis ----
    const float rr = r * (1.0f / R_C);
    const float cosp = __cosf(3.14159265358979323846f * rr);
    const float half_fc = (valid && (r < R_C)) ? (0.25f * cosp + 0.25f) : 0.0f;

    const float x = 2.0f * (rr - 1.0f) * (rr - 1.0f) - 1.0f;

    float fn0 = 1.0f, fn1 = x;
    float f[K_MAX];
    f[0] = (fn0 + 1.0f) * half_fc;
    f[1] = (fn1 + 1.0f) * half_fc;
    #pragma unroll
    for (int k = 2; k < K_MAX; ++k) {
        const float fnk = 2.0f * x * fn1 - fn0;
        f[k] = (fnk + 1.0f) * half_fc;
        fn0 = fn1; fn1 = fnk;
    }

    // ---- per-edge matvec: acc[d] = sum_k c[ta][tn][d][k] * f[k] ----
    const int cb = ta * N_TYPES + tn;
    float acc[N_DESC];
    #pragma unroll
    for (int d = 0; d < N_DESC; ++d) {
        float s = 0.0f;
        #pragma unroll
        for (int k = 0; k < K_MAX; ++k)
            s += ld_c[(d * K_MAX + k) * 16 + cb] * f[k];
        acc[d] = s;
    }

    // ---- two-level reduction: 24 + 3 shuffles instead of 48 ----
    // Stage A: butterfly strides 1,2,4 on all 8 accs -> every lane holds its
    // 8-lane group's partial for every descriptor.
    #pragma unroll
    for (int d = 0; d < N_DESC; ++d) {
        float v = acc[d];
        v += __shfl_xor(v, 1, 64);
        v += __shfl_xor(v, 2, 64);
        v += __shfl_xor(v, 4, 64);
        acc[d] = v;
    }
    // Stage B: lane l takes descriptor (l&7), butterfly strides 8,16,32
    // across the 8 groups.
    float v = acc[0];
    #pragma unroll
    for (int d = 1; d < N_DESC; ++d)
        v = ((lane & 7) == d) ? acc[d] : v;
    v += __shfl_xor(v, 8, 64);
    v += __shfl_xor(v, 16, 64);
    v += __shfl_xor(v, 32, 64);

    if (lane < 8)
        out[(size_t)a * N_DESC + lane] = v;   // coalesced 32B store
}

extern "C" void kernel_launch(void* const* d_in, const int* in_sizes, int n_in,
                              void* d_out, int out_size, void* d_ws, size_t ws_size,
                              hipStream_t stream) {
    const int*   types            = (const int*)d_in[0];
    const float* positions        = (const float*)d_in[1];
    const int*   radial_neighbors = (const int*)d_in[2];
    const float* radial_offsets   = (const float*)d_in[3];
    const float* c_table          = (const float*)d_in[4];
    float* out = (float*)d_out;
    float4* packed = (float4*)d_ws;

    const int n_atoms = in_sizes[0];

    pack_pos_type<<<(n_atoms + 255) / 256, 256, 0, stream>>>(
        types, positions, packed, n_atoms);

    radial_desc_kernel<<<(n_atoms + 3) / 4, 256, 0, stream>>>(
        packed, radial_neighbors, radial_offsets, c_table, out, n_atoms);
}